// Round 10
// baseline (333.866 us; speedup 1.0000x reference)
//
#include <hip/hip_runtime.h>
#include <math.h>

#define N_NODES 20000
#define N_EDGES 160000
#define NODE_DIM 64
#define EDGE_DIM 16
#define H 32
#define STEPS 3

// ---------------------------------------------------------------------------
// Dual-CSR setup (src-sorted edges for fused_msg locality; dst-slot map so
// fused_msg scatter-STORES to unique dst-sorted slots and gru gathers
// CONTIGUOUS rows — no atomic RMW on the message path).
//   memset:  cursor_s + cursor_d (contiguous, one fill)
//   hist:    src + dst degree histograms (one kernel, 2 atomics/edge)
//   scan_a:  158 blocks — per-256-chunk exclusive scan (0..78 src, 79..157 dst)
//   scan_b:  2 blocks — chunk-offset fixup; cursor_* = rowptr_*
//   fill:    slot = cursor_s[src]++; slot_d = cursor_d[dst]++;
//            eperm[slot] = e; ss2[slot] = (src, slot_d)
//   permute: ef2[slot] = ef[eperm[slot]]   (coalesced writes)
// ---------------------------------------------------------------------------
__global__ void hist_kernel(const int* __restrict__ ei,
                            int* __restrict__ deg_s,
                            int* __restrict__ deg_d) {
    int e = blockIdx.x * 256 + threadIdx.x;
    if (e < N_EDGES) {
        atomicAdd(&deg_s[ei[e]], 1);
        atomicAdd(&deg_d[ei[N_EDGES + e]], 1);
    }
}

__global__ void scan_a_kernel(const int* __restrict__ deg_s,
                              const int* __restrict__ deg_d,
                              int* __restrict__ part_s,
                              int* __restrict__ part_d,
                              int* __restrict__ bsum) {
    __shared__ int s[256];
    int which = (blockIdx.x >= 79);
    const int* __restrict__ deg = which ? deg_d : deg_s;
    int* __restrict__ part      = which ? part_d : part_s;
    int b = which ? (blockIdx.x - 79) : blockIdx.x;
    int v = b * 256 + threadIdx.x;
    int x = (v < N_NODES) ? deg[v] : 0;
    s[threadIdx.x] = x;
    __syncthreads();
    for (int off = 1; off < 256; off <<= 1) {
        int t = (threadIdx.x >= off) ? s[threadIdx.x - off] : 0;
        __syncthreads();
        s[threadIdx.x] += t;
        __syncthreads();
    }
    if (v < N_NODES) part[v] = s[threadIdx.x] - x;
    if (threadIdx.x == 255) bsum[blockIdx.x] = s[255];
}

__global__ void scan_b_kernel(int* __restrict__ rowptr_s,
                              int* __restrict__ rowptr_d,
                              const int* __restrict__ bsum,
                              int* __restrict__ cursor_s,
                              int* __restrict__ cursor_d) {
    __shared__ int boff[80];
    int which = blockIdx.x;                       // 0 = src, 1 = dst
    int* __restrict__ rowptr = which ? rowptr_d : rowptr_s;
    int* __restrict__ cursor = which ? cursor_d : cursor_s;
    const int* __restrict__ bs = bsum + which * 79;
    if (threadIdx.x == 0) {
        int run = 0;
        for (int b = 0; b < 79; ++b) { boff[b] = run; run += bs[b]; }
    }
    __syncthreads();
    for (int v = threadIdx.x; v < N_NODES; v += 256) {
        int r = rowptr[v] + boff[v >> 8];
        rowptr[v] = r;
        cursor[v] = r;
    }
    if (threadIdx.x == 0) rowptr[N_NODES] = N_EDGES;
}

__global__ void fill_kernel(const int* __restrict__ ei,
                            int* __restrict__ cursor_s,
                            int* __restrict__ cursor_d,
                            int* __restrict__ eperm,
                            int2* __restrict__ ss2) {
    int e = blockIdx.x * 256 + threadIdx.x;
    if (e < N_EDGES) {
        int s = ei[e];
        int d = ei[N_EDGES + e];
        int slot   = atomicAdd(&cursor_s[s], 1);
        int slot_d = atomicAdd(&cursor_d[d], 1);
        eperm[slot] = e;
        ss2[slot]   = make_int2(s, slot_d);
    }
}

__global__ void permute_ef_kernel(const float* __restrict__ ef,
                                  const int* __restrict__ eperm,
                                  float* __restrict__ ef2) {
    int t = blockIdx.x * 256 + threadIdx.x;
    if (t < N_EDGES * EDGE_DIM) {
        int j = t >> 4;
        int d = t & 15;
        ef2[t] = ef[eperm[j] * EDGE_DIM + d];
    }
}

// ---------------------------------------------------------------------------
// node projection: h = node_feat @ W_np.T + b_np
// ---------------------------------------------------------------------------
__global__ void node_proj_kernel(const float* __restrict__ nf,
                                 const float* __restrict__ W,
                                 const float* __restrict__ b,
                                 float* __restrict__ h) {
    int tid = blockIdx.x * blockDim.x + threadIdx.x;
    if (tid >= N_NODES * H) return;
    int v = tid >> 5;
    int i = tid & 31;
    const float* __restrict__ row = nf + v * NODE_DIM;
    const float* __restrict__ w   = W + i * NODE_DIM;
    float acc = b[i];
#pragma unroll
    for (int d = 0; d < NODE_DIM; ++d) acc = fmaf(row[d], w[d], acc);
    h[tid] = acc;
}

// ---------------------------------------------------------------------------
// FUSED U-precompute + edge message (U lives only in LDS, never HBM).
// Phase 1 (proven R7): thread t owns column c=t; h rows staged in 2KB LDS,
//   read as same-address broadcast float4. Swizzled U layout:
//   col c = i*16+4q+e -> Ul[n*576 + q*136 + i*4 + e]; bias i -> 544+i.
// Phase 2 (proven R7 loop; NEW sink): contiguous per-half-wave chunks,
//   reg-cached U (reload on src change), 1-deep prefetch of (ss, ef).
//   Sink is now a PLAIN STORE to the edge's unique dst-sorted slot
//   (ss.y) — removes the ~500 GB/s f32 atomic-RMW floor measured via
//   WRITE_SIZE == E*H*4B at 40us/step.
// ---------------------------------------------------------------------------
__global__ __launch_bounds__(576)
void fused_msg_kernel(const float* __restrict__ We,
                      const float* __restrict__ be,
                      const float* __restrict__ h,
                      const int* __restrict__ rowptr,
                      const int2* __restrict__ ss2,
                      const float* __restrict__ ef2,
                      float* __restrict__ msg_out) {
    __shared__ float hs[16 * 32];     // 2 KB
    __shared__ float Ul[16 * 576];    // 36 KB (swizzled, 576-float row stride)

    int t = threadIdx.x;

    // ---- per-thread weight column (registers) ----
    float wreg[32];
    int p = -1;
    if (t < 512) {
        int L = t >> 4, q = (t >> 2) & 3, e = t & 3;
        int d = t & 15;
#pragma unroll
        for (int k = 0; k < H; ++k) wreg[k] = We[(L * H + k) * EDGE_DIM + d];
        p = q * 136 + L * 4 + e;
    } else if (t < 544) {
        int i = t - 512;
#pragma unroll
        for (int k = 0; k < H; ++k) wreg[k] = be[i * H + k];
        p = 544 + i;
    }

    int v0 = blockIdx.x * 16;

    // ---- stage h rows ----
    if (t < 512) hs[t] = h[(size_t)v0 * H + t];
    __syncthreads();

    // ---- phase 1: U into LDS (2 nodes per pass, broadcast f4 reads) ----
    if (p >= 0) {
        for (int n = 0; n < 16; n += 2) {
            const float4* __restrict__ hp0 = (const float4*)(hs + n * H);
            const float4* __restrict__ hp1 = (const float4*)(hs + (n + 1) * H);
            float a0 = 0.f, a1 = 0.f;
#pragma unroll
            for (int kk = 0; kk < 8; ++kk) {
                float4 q0 = hp0[kk];
                float4 q1 = hp1[kk];
                a0 = fmaf(wreg[4 * kk + 0], q0.x, a0);
                a1 = fmaf(wreg[4 * kk + 0], q1.x, a1);
                a0 = fmaf(wreg[4 * kk + 1], q0.y, a0);
                a1 = fmaf(wreg[4 * kk + 1], q1.y, a1);
                a0 = fmaf(wreg[4 * kk + 2], q0.z, a0);
                a1 = fmaf(wreg[4 * kk + 2], q1.z, a1);
                a0 = fmaf(wreg[4 * kk + 3], q0.w, a0);
                a1 = fmaf(wreg[4 * kk + 3], q1.w, a1);
            }
            Ul[n * 576 + p]       = a0;
            Ul[(n + 1) * 576 + p] = a1;
        }
    }
    __syncthreads();

    // ---- phase 2: contiguous chunks, reg-cached U, 1-deep prefetch ----
    int hw    = t >> 5;          // 0..17
    int lane  = t & 31;          // output component i
    int jbeg  = rowptr[v0];
    int jend  = rowptr[v0 + 16];
    int nE    = jend - jbeg;
    int chunk = (nE + 17) / 18;
    int ja    = jbeg + hw * chunk;
    int jz    = ja + chunk; if (jz > jend) jz = jend;

    if (ja < jz) {
        int s_prev = -1;
        float4 u0 = {0,0,0,0}, u1 = {0,0,0,0}, u2 = {0,0,0,0}, u3 = {0,0,0,0};
        float  bv = 0.f;

        int2 ss = ss2[ja];
        const float4* __restrict__ ep0 = (const float4*)(ef2 + (size_t)ja * EDGE_DIM);
        float4 e0 = ep0[0], e1 = ep0[1], e2 = ep0[2], e3 = ep0[3];

        for (int j = ja; j < jz; ++j) {
            // prefetch next edge (clamped -> no branch)
            int jn = (j + 1 < jz) ? (j + 1) : j;
            int2 ssn = ss2[jn];
            const float4* __restrict__ epn =
                (const float4*)(ef2 + (size_t)jn * EDGE_DIM);
            float4 f0 = epn[0], f1 = epn[1], f2 = epn[2], f3 = epn[3];

            // U regs reload only on src change
            if (ss.x != s_prev) {
                s_prev = ss.x;
                int ls = ss.x - v0;
                const float4* __restrict__ up = (const float4*)(Ul + ls * 576);
                u0 = up[0 * 34 + lane];
                u1 = up[1 * 34 + lane];
                u2 = up[2 * 34 + lane];
                u3 = up[3 * 34 + lane];
                bv = Ul[ls * 576 + 544 + lane];
            }

            float msg = bv;
            msg = fmaf(e0.x, u0.x, msg);
            msg = fmaf(e0.y, u0.y, msg);
            msg = fmaf(e0.z, u0.z, msg);
            msg = fmaf(e0.w, u0.w, msg);
            msg = fmaf(e1.x, u1.x, msg);
            msg = fmaf(e1.y, u1.y, msg);
            msg = fmaf(e1.z, u1.z, msg);
            msg = fmaf(e1.w, u1.w, msg);
            msg = fmaf(e2.x, u2.x, msg);
            msg = fmaf(e2.y, u2.y, msg);
            msg = fmaf(e2.z, u2.z, msg);
            msg = fmaf(e2.w, u2.w, msg);
            msg = fmaf(e3.x, u3.x, msg);
            msg = fmaf(e3.y, u3.y, msg);
            msg = fmaf(e3.z, u3.z, msg);
            msg = fmaf(e3.w, u3.w, msg);

            // unique dst-sorted slot: plain streaming store, no RMW
            msg_out[(size_t)ss.y * H + lane] = msg;

            ss = ssn;
            e0 = f0; e1 = f1; e2 = f2; e3 = f3;
        }
    }
}

// ---------------------------------------------------------------------------
// GRU: register-weight column-GEMM (proven) + contiguous dst-CSR gather of
// msg rows in phase A (4 independent accumulators -> load-latency tolerant;
// rows are L2-resident: written by fused_msg just before). No m buffer.
// ---------------------------------------------------------------------------
__global__ __launch_bounds__(256, 4)
void gru_kernel(const float* __restrict__ Wih,
                const float* __restrict__ Whh,
                const float* __restrict__ bih,
                const float* __restrict__ bhh,
                const float* __restrict__ msg,
                const int* __restrict__ rowptr_d,
                const float* __restrict__ h,
                float* __restrict__ hout) {
    __shared__ float xs[16 * 64];        // [node][ m(32) | h(32) ]   4 KB
    __shared__ float gs[16 * 32 * 5];    // [node][i][gate + pad]    10 KB

    int c = threadIdx.x & 127;
    float4 wc[16];
    if (c < 96) {
        const float4* p = (const float4*)(Wih + c * H);
#pragma unroll
        for (int q = 0; q < 8; ++q) wc[q] = p[q];
    } else {
#pragma unroll
        for (int q = 0; q < 8; ++q) wc[q] = make_float4(0.f, 0.f, 0.f, 0.f);
    }
    int hrow = (c < 64) ? c : ((c >= 96) ? (c - 32) : -1);
    if (hrow >= 0) {
        const float4* p = (const float4*)(Whh + hrow * H);
#pragma unroll
        for (int q = 0; q < 8; ++q) wc[8 + q] = p[q];
    } else {
#pragma unroll
        for (int q = 0; q < 8; ++q) wc[8 + q] = make_float4(0.f, 0.f, 0.f, 0.f);
    }
    float bias;
    if (c < 64)      bias = bih[c] + bhh[c];      // r_sum / z_sum
    else if (c < 96) bias = bih[c];               // in
    else             bias = bhh[c - 32];          // hn

    int g    = threadIdx.x >> 5;    // node group 0..7
    int lane = threadIdx.x & 31;
    int half = threadIdx.x >> 7;    // 0: nodes 0..7, 1: nodes 8..15
    int ci   = c & 31;
    int gt   = c >> 5;

    int v0 = blockIdx.x * 16;
    {
        // ---- phase A: contiguous msg gather (4-wide ILP) + h stage ----
#pragma unroll
        for (int nn = 0; nn < 2; ++nn) {
            int n = g + nn * 8;
            int v = v0 + n;
            int beg = rowptr_d[v], end = rowptr_d[v + 1];
            int cnt = end - beg;
            const float* __restrict__ mp = msg + (size_t)beg * H + lane;
            float a0 = 0.f, a1 = 0.f, a2 = 0.f, a3 = 0.f;
            int pp = 0;
            for (; pp + 4 <= cnt; pp += 4) {
                float x0 = mp[0 * H];
                float x1 = mp[1 * H];
                float x2 = mp[2 * H];
                float x3 = mp[3 * H];
                a0 += x0; a1 += x1; a2 += x2; a3 += x3;
                mp += 4 * H;
            }
            for (; pp < cnt; ++pp) { a0 += mp[0]; mp += H; }
            xs[n * 64 + lane]      = (a0 + a1) + (a2 + a3);
            xs[n * 64 + 32 + lane] = h[(size_t)v * H + lane];
        }
        __syncthreads();

        // ---- phase B: column-GEMM, 2 nodes per pass for ILP ----
#pragma unroll
        for (int n = 0; n < 8; n += 2) {
            const float4* x0 = (const float4*)(xs + (half * 8 + n) * 64);
            const float4* x1 = (const float4*)(xs + (half * 8 + n + 1) * 64);
            float acc0 = bias, acc1 = bias;
#pragma unroll
            for (int q = 0; q < 16; ++q) {
                float4 w = wc[q];
                float4 a = x0[q];
                float4 b = x1[q];
                acc0 = fmaf(w.x, a.x, acc0); acc1 = fmaf(w.x, b.x, acc1);
                acc0 = fmaf(w.y, a.y, acc0); acc1 = fmaf(w.y, b.y, acc1);
                acc0 = fmaf(w.z, a.z, acc0); acc1 = fmaf(w.z, b.z, acc1);
                acc0 = fmaf(w.w, a.w, acc0); acc1 = fmaf(w.w, b.w, acc1);
            }
            gs[((half * 8 + n)     * 32 + ci) * 5 + gt] = acc0;
            gs[((half * 8 + n + 1) * 32 + ci) * 5 + gt] = acc1;
        }
        __syncthreads();

        // ---- phase C: gates + output ----
        for (int t = threadIdx.x; t < 16 * 32; t += 256) {
            int nl = t >> 5, ii = t & 31;
            const float* gp = gs + (size_t)t * 5;
            float rs = gp[0], zs = gp[1], in_ = gp[2], hn = gp[3];
            float hv = xs[nl * 64 + 32 + ii];
            float r   = 1.f / (1.f + __expf(-rs));
            float z   = 1.f / (1.f + __expf(-zs));
            float nn2 = tanhf(in_ + r * hn);
            hout[(size_t)(v0 + nl) * H + ii] = (1.f - z) * nn2 + z * hv;
        }
    }
}

// ---------------------------------------------------------------------------
extern "C" void kernel_launch(void* const* d_in, const int* in_sizes, int n_in,
                              void* d_out, int out_size, void* d_ws, size_t ws_size,
                              hipStream_t stream) {
    const float* node_feat = (const float*)d_in[0];
    const int*   edge_idx  = (const int*)  d_in[1];
    const float* edge_feat = (const float*)d_in[2];
    const float* W_np      = (const float*)d_in[3];
    const float* b_np      = (const float*)d_in[4];
    const float* W_e       = (const float*)d_in[5];
    const float* b_e       = (const float*)d_in[6];
    const float* W_ih      = (const float*)d_in[7];
    const float* W_hh      = (const float*)d_in[8];
    const float* b_ih      = (const float*)d_in[9];
    const float* b_hh      = (const float*)d_in[10];

    float* h       = (float*)d_ws;                              // N*H
    float* msg     = h + (size_t)N_NODES * H;                   // E*H (20.5 MB)
    float* ef2     = msg + (size_t)N_EDGES * H;                 // E*EDGE_DIM
    int* rowptr_s  = (int*)(ef2 + (size_t)N_EDGES * EDGE_DIM);  // N+1
    int* rowptr_d  = rowptr_s + (N_NODES + 1);                  // N+1
    int* cursor_s  = rowptr_d + (N_NODES + 1);                  // N  (contig with
    int* cursor_d  = cursor_s + N_NODES;                        // N   cursor_d)
    int* bsum      = cursor_d + N_NODES;                        // 158 (+pad 160)
    int* eperm     = bsum + 160;                                // E
    int2* ss2      = (int2*)(eperm + N_EDGES);                  // E int2
    float* out     = (float*)d_out;

    // ---- setup (7 small dispatches, no grid.sync, no m buffer) ----
    hipMemsetAsync(cursor_s, 0, 2 * N_NODES * sizeof(int), stream);
    hist_kernel<<<(N_EDGES + 255) / 256, 256, 0, stream>>>(edge_idx,
                                                           cursor_s, cursor_d);
    scan_a_kernel<<<158, 256, 0, stream>>>(cursor_s, cursor_d,
                                           rowptr_s, rowptr_d, bsum);
    scan_b_kernel<<<2, 256, 0, stream>>>(rowptr_s, rowptr_d, bsum,
                                         cursor_s, cursor_d);
    fill_kernel<<<(N_EDGES + 255) / 256, 256, 0, stream>>>(edge_idx, cursor_s,
                                                           cursor_d, eperm, ss2);
    permute_ef_kernel<<<(N_EDGES * EDGE_DIM + 255) / 256, 256, 0, stream>>>(
        edge_feat, eperm, ef2);
    node_proj_kernel<<<(N_NODES * H + 255) / 256, 256, 0, stream>>>(
        node_feat, W_np, b_np, h);

    // ---- 3 propagation steps (2 dispatches each) ----
    for (int step = 0; step < STEPS; ++step) {
        fused_msg_kernel<<<N_NODES / 16, 576, 0, stream>>>(
            W_e, b_e, h, rowptr_s, ss2, ef2, msg);
        float* dst_h = (step == STEPS - 1) ? out : h;
        gru_kernel<<<N_NODES / 16, 256, 0, stream>>>(W_ih, W_hh, b_ih, b_hh,
                                                     msg, rowptr_d, h, dst_h);
    }
}

// Round 11
// 298.498 us; speedup vs baseline: 1.1185x; 1.1185x over previous
//
#include <hip/hip_runtime.h>
#include <math.h>

#define N_NODES 20000
#define N_EDGES 160000
#define NODE_DIM 64
#define EDGE_DIM 16
#define H 32
#define STEPS 3

// ---------------------------------------------------------------------------
// CSR-by-src build. R7 shape (proven fastest), with ONE change: fill copies
// the edge-feature row inline (drops the separate permute dispatch + the
// eperm array + a full 20MB read/write pass). 7 setup enqueues total.
// ---------------------------------------------------------------------------
__global__ void hist_src_kernel(const int* __restrict__ ei, int* __restrict__ deg) {
    int e = blockIdx.x * 256 + threadIdx.x;
    if (e < N_EDGES) atomicAdd(&deg[ei[e]], 1);               // row 0 = src
}

__global__ void scan_a_kernel(const int* __restrict__ deg,
                              int* __restrict__ part, int* __restrict__ bsum) {
    __shared__ int s[256];
    int v = blockIdx.x * 256 + threadIdx.x;
    int x = (v < N_NODES) ? deg[v] : 0;
    s[threadIdx.x] = x;
    __syncthreads();
    for (int off = 1; off < 256; off <<= 1) {
        int t = (threadIdx.x >= off) ? s[threadIdx.x - off] : 0;
        __syncthreads();
        s[threadIdx.x] += t;
        __syncthreads();
    }
    if (v < N_NODES) part[v] = s[threadIdx.x] - x;
    if (threadIdx.x == 255) bsum[blockIdx.x] = s[255];
}

__global__ void scan_b_kernel(int* __restrict__ rowptr,
                              const int* __restrict__ bsum,
                              int* __restrict__ cursor) {
    __shared__ int boff[80];
    if (threadIdx.x == 0) {
        int run = 0;
        for (int b = 0; b < 79; ++b) { boff[b] = run; run += bsum[b]; }
    }
    __syncthreads();
    for (int v = threadIdx.x; v < N_NODES; v += 256) {
        int r = rowptr[v] + boff[v >> 8];
        rowptr[v] = r;
        cursor[v] = r;
    }
    if (threadIdx.x == 0) rowptr[N_NODES] = N_EDGES;
}

// fill + inline ef permute (scattered 64B row copies; saves a full pass)
__global__ void fill_src_kernel(const int* __restrict__ ei,
                                const float* __restrict__ ef,
                                int* __restrict__ cursor,
                                int2* __restrict__ sd2,
                                float* __restrict__ ef2) {
    int e = blockIdx.x * 256 + threadIdx.x;
    if (e < N_EDGES) {
        int s = ei[e];
        int slot = atomicAdd(&cursor[s], 1);
        sd2[slot] = make_int2(s, ei[N_EDGES + e]);
        const float4* __restrict__ srcp = (const float4*)(ef + (size_t)e * EDGE_DIM);
        float4* __restrict__ dstp       = (float4*)(ef2 + (size_t)slot * EDGE_DIM);
        float4 a = srcp[0], b = srcp[1], c = srcp[2], d = srcp[3];
        dstp[0] = a; dstp[1] = b; dstp[2] = c; dstp[3] = d;
    }
}

// ---------------------------------------------------------------------------
// node projection: h = node_feat @ W_np.T + b_np
// ---------------------------------------------------------------------------
__global__ void node_proj_kernel(const float* __restrict__ nf,
                                 const float* __restrict__ W,
                                 const float* __restrict__ b,
                                 float* __restrict__ h) {
    int tid = blockIdx.x * blockDim.x + threadIdx.x;
    if (tid >= N_NODES * H) return;
    int v = tid >> 5;
    int i = tid & 31;
    const float* __restrict__ row = nf + v * NODE_DIM;
    const float* __restrict__ w   = W + i * NODE_DIM;
    float acc = b[i];
#pragma unroll
    for (int d = 0; d < NODE_DIM; ++d) acc = fmaf(row[d], w[d], acc);
    h[tid] = acc;
}

// ---------------------------------------------------------------------------
// FUSED U-precompute + edge message — EXACT R7 version (proven best, 303us
// total). U lives only in LDS. Atomic scatter into m is the cheapest sink
// (store+gather alternatives measured slower 3x: R1/R2, R10).
// Phase 1: thread t owns column c=t; h rows staged in 2KB LDS, read as
//   same-address broadcast float4. Swizzled U layout:
//   col c = i*16+4q+e -> Ul[n*576 + q*136 + i*4 + e]; bias i -> 544+i.
// Phase 2: contiguous per-half-wave chunks, reg-cached U (reload on src
//   change), 1-deep prefetch of (sd, ef) hides VMEM latency.
// ---------------------------------------------------------------------------
__global__ __launch_bounds__(576)
void fused_msg_kernel(const float* __restrict__ We,
                      const float* __restrict__ be,
                      const float* __restrict__ h,
                      const int* __restrict__ rowptr,
                      const int2* __restrict__ sd2,
                      const float* __restrict__ ef2,
                      float* __restrict__ m) {
    __shared__ float hs[16 * 32];     // 2 KB
    __shared__ float Ul[16 * 576];    // 36 KB (swizzled, 576-float row stride)

    int t = threadIdx.x;

    // ---- per-thread weight column (registers) ----
    float wreg[32];
    int p = -1;
    if (t < 512) {
        int L = t >> 4, q = (t >> 2) & 3, e = t & 3;
        int d = t & 15;
#pragma unroll
        for (int k = 0; k < H; ++k) wreg[k] = We[(L * H + k) * EDGE_DIM + d];
        p = q * 136 + L * 4 + e;
    } else if (t < 544) {
        int i = t - 512;
#pragma unroll
        for (int k = 0; k < H; ++k) wreg[k] = be[i * H + k];
        p = 544 + i;
    }

    int v0 = blockIdx.x * 16;

    // ---- stage h rows ----
    if (t < 512) hs[t] = h[(size_t)v0 * H + t];
    __syncthreads();

    // ---- phase 1: U into LDS (2 nodes per pass, broadcast f4 reads) ----
    if (p >= 0) {
        for (int n = 0; n < 16; n += 2) {
            const float4* __restrict__ hp0 = (const float4*)(hs + n * H);
            const float4* __restrict__ hp1 = (const float4*)(hs + (n + 1) * H);
            float a0 = 0.f, a1 = 0.f;
#pragma unroll
            for (int kk = 0; kk < 8; ++kk) {
                float4 q0 = hp0[kk];
                float4 q1 = hp1[kk];
                a0 = fmaf(wreg[4 * kk + 0], q0.x, a0);
                a1 = fmaf(wreg[4 * kk + 0], q1.x, a1);
                a0 = fmaf(wreg[4 * kk + 1], q0.y, a0);
                a1 = fmaf(wreg[4 * kk + 1], q1.y, a1);
                a0 = fmaf(wreg[4 * kk + 2], q0.z, a0);
                a1 = fmaf(wreg[4 * kk + 2], q1.z, a1);
                a0 = fmaf(wreg[4 * kk + 3], q0.w, a0);
                a1 = fmaf(wreg[4 * kk + 3], q1.w, a1);
            }
            Ul[n * 576 + p]       = a0;
            Ul[(n + 1) * 576 + p] = a1;
        }
    }
    __syncthreads();

    // ---- phase 2: contiguous chunks, reg-cached U, 1-deep prefetch ----
    int hw    = t >> 5;          // 0..17
    int lane  = t & 31;          // output component i
    int jbeg  = rowptr[v0];
    int jend  = rowptr[v0 + 16];
    int nE    = jend - jbeg;
    int chunk = (nE + 17) / 18;
    int ja    = jbeg + hw * chunk;
    int jz    = ja + chunk; if (jz > jend) jz = jend;

    if (ja < jz) {
        int s_prev = -1;
        float4 u0 = {0,0,0,0}, u1 = {0,0,0,0}, u2 = {0,0,0,0}, u3 = {0,0,0,0};
        float  bv = 0.f;

        int2 sd = sd2[ja];
        const float4* __restrict__ ep0 = (const float4*)(ef2 + (size_t)ja * EDGE_DIM);
        float4 e0 = ep0[0], e1 = ep0[1], e2 = ep0[2], e3 = ep0[3];

        for (int j = ja; j < jz; ++j) {
            // prefetch next edge (clamped -> no branch)
            int jn = (j + 1 < jz) ? (j + 1) : j;
            int2 sdn = sd2[jn];
            const float4* __restrict__ epn =
                (const float4*)(ef2 + (size_t)jn * EDGE_DIM);
            float4 f0 = epn[0], f1 = epn[1], f2 = epn[2], f3 = epn[3];

            // U regs reload only on src change
            if (sd.x != s_prev) {
                s_prev = sd.x;
                int ls = sd.x - v0;
                const float4* __restrict__ up = (const float4*)(Ul + ls * 576);
                u0 = up[0 * 34 + lane];
                u1 = up[1 * 34 + lane];
                u2 = up[2 * 34 + lane];
                u3 = up[3 * 34 + lane];
                bv = Ul[ls * 576 + 544 + lane];
            }

            float msg = bv;
            msg = fmaf(e0.x, u0.x, msg);
            msg = fmaf(e0.y, u0.y, msg);
            msg = fmaf(e0.z, u0.z, msg);
            msg = fmaf(e0.w, u0.w, msg);
            msg = fmaf(e1.x, u1.x, msg);
            msg = fmaf(e1.y, u1.y, msg);
            msg = fmaf(e1.z, u1.z, msg);
            msg = fmaf(e1.w, u1.w, msg);
            msg = fmaf(e2.x, u2.x, msg);
            msg = fmaf(e2.y, u2.y, msg);
            msg = fmaf(e2.z, u2.z, msg);
            msg = fmaf(e2.w, u2.w, msg);
            msg = fmaf(e3.x, u3.x, msg);
            msg = fmaf(e3.y, u3.y, msg);
            msg = fmaf(e3.z, u3.z, msg);
            msg = fmaf(e3.w, u3.w, msg);

            atomicAdd(&m[(size_t)sd.y * H + lane], msg);

            sd = sdn;
            e0 = f0; e1 = f1; e2 = f2; e3 = f3;
        }
    }
}

// ---------------------------------------------------------------------------
// GRU — EXACT R7 version (proven): register-weight column-GEMM, xs LDS
// staging, self-zero of m for the next step's atomics.
// ---------------------------------------------------------------------------
__global__ __launch_bounds__(256, 4)
void gru_kernel(const float* __restrict__ Wih,
                const float* __restrict__ Whh,
                const float* __restrict__ bih,
                const float* __restrict__ bhh,
                float* __restrict__ m,
                const float* __restrict__ h,
                float* __restrict__ hout) {
    __shared__ float xs[16 * 64];        // [node][ m(32) | h(32) ]   4 KB
    __shared__ float gs[16 * 32 * 5];    // [node][i][gate + pad]    10 KB

    int c = threadIdx.x & 127;
    float4 wc[16];
    if (c < 96) {
        const float4* p = (const float4*)(Wih + c * H);
#pragma unroll
        for (int q = 0; q < 8; ++q) wc[q] = p[q];
    } else {
#pragma unroll
        for (int q = 0; q < 8; ++q) wc[q] = make_float4(0.f, 0.f, 0.f, 0.f);
    }
    int hrow = (c < 64) ? c : ((c >= 96) ? (c - 32) : -1);
    if (hrow >= 0) {
        const float4* p = (const float4*)(Whh + hrow * H);
#pragma unroll
        for (int q = 0; q < 8; ++q) wc[8 + q] = p[q];
    } else {
#pragma unroll
        for (int q = 0; q < 8; ++q) wc[8 + q] = make_float4(0.f, 0.f, 0.f, 0.f);
    }
    float bias;
    if (c < 64)      bias = bih[c] + bhh[c];      // r_sum / z_sum
    else if (c < 96) bias = bih[c];               // in
    else             bias = bhh[c - 32];          // hn

    int g    = threadIdx.x >> 5;    // node group 0..7
    int lane = threadIdx.x & 31;
    int half = threadIdx.x >> 7;    // 0: nodes 0..7, 1: nodes 8..15
    int ci   = c & 31;
    int gt   = c >> 5;

    int v0 = blockIdx.x * 16;
    {
        // ---- phase A: read m (and zero it), stage h ----
#pragma unroll
        for (int nn = 0; nn < 2; ++nn) {
            int n = g + nn * 8;
            int v = v0 + n;
            float mv = m[(size_t)v * H + lane];
            m[(size_t)v * H + lane] = 0.f;       // pre-zero for next step
            xs[n * 64 + lane]      = mv;
            xs[n * 64 + 32 + lane] = h[(size_t)v * H + lane];
        }
        __syncthreads();

        // ---- phase B: column-GEMM, 2 nodes per pass for ILP ----
#pragma unroll
        for (int n = 0; n < 8; n += 2) {
            const float4* x0 = (const float4*)(xs + (half * 8 + n) * 64);
            const float4* x1 = (const float4*)(xs + (half * 8 + n + 1) * 64);
            float acc0 = bias, acc1 = bias;
#pragma unroll
            for (int q = 0; q < 16; ++q) {
                float4 w = wc[q];
                float4 a = x0[q];
                float4 b = x1[q];
                acc0 = fmaf(w.x, a.x, acc0); acc1 = fmaf(w.x, b.x, acc1);
                acc0 = fmaf(w.y, a.y, acc0); acc1 = fmaf(w.y, b.y, acc1);
                acc0 = fmaf(w.z, a.z, acc0); acc1 = fmaf(w.z, b.z, acc1);
                acc0 = fmaf(w.w, a.w, acc0); acc1 = fmaf(w.w, b.w, acc1);
            }
            gs[((half * 8 + n)     * 32 + ci) * 5 + gt] = acc0;
            gs[((half * 8 + n + 1) * 32 + ci) * 5 + gt] = acc1;
        }
        __syncthreads();

        // ---- phase C: gates + output ----
        for (int t = threadIdx.x; t < 16 * 32; t += 256) {
            int nl = t >> 5, ii = t & 31;
            const float* gp = gs + (size_t)t * 5;
            float rs = gp[0], zs = gp[1], in_ = gp[2], hn = gp[3];
            float hv = xs[nl * 64 + 32 + ii];
            float r   = 1.f / (1.f + __expf(-rs));
            float z   = 1.f / (1.f + __expf(-zs));
            float nn2 = tanhf(in_ + r * hn);
            hout[(size_t)(v0 + nl) * H + ii] = (1.f - z) * nn2 + z * hv;
        }
    }
}

// ---------------------------------------------------------------------------
extern "C" void kernel_launch(void* const* d_in, const int* in_sizes, int n_in,
                              void* d_out, int out_size, void* d_ws, size_t ws_size,
                              hipStream_t stream) {
    const float* node_feat = (const float*)d_in[0];
    const int*   edge_idx  = (const int*)  d_in[1];
    const float* edge_feat = (const float*)d_in[2];
    const float* W_np      = (const float*)d_in[3];
    const float* b_np      = (const float*)d_in[4];
    const float* W_e       = (const float*)d_in[5];
    const float* b_e       = (const float*)d_in[6];
    const float* W_ih      = (const float*)d_in[7];
    const float* W_hh      = (const float*)d_in[8];
    const float* b_ih      = (const float*)d_in[9];
    const float* b_hh      = (const float*)d_in[10];

    float* h      = (float*)d_ws;                             // N*H
    float* m      = h + (size_t)N_NODES * H;                  // N*H
    float* ef2    = m + (size_t)N_NODES * H;                  // E*EDGE_DIM
    int* rowptr   = (int*)(ef2 + (size_t)N_EDGES * EDGE_DIM); // N+1
    int* cursor   = rowptr + (N_NODES + 1);                   // N
    int* bsum     = cursor + N_NODES;                         // 81 (pad -> sd2 8B-aligned)
    int2* sd2     = (int2*)(bsum + 81);                       // E int2
    float* out    = (float*)d_out;

    // ---- setup: 7 enqueues (R7 shape, permute folded into fill) ----
    hipMemsetAsync(m, 0, (size_t)N_NODES * H * sizeof(float), stream);
    hipMemsetAsync(cursor, 0, N_NODES * sizeof(int), stream);
    hist_src_kernel<<<(N_EDGES + 255) / 256, 256, 0, stream>>>(edge_idx, cursor);
    scan_a_kernel<<<(N_NODES + 255) / 256, 256, 0, stream>>>(cursor, rowptr, bsum);
    scan_b_kernel<<<1, 256, 0, stream>>>(rowptr, bsum, cursor);
    fill_src_kernel<<<(N_EDGES + 255) / 256, 256, 0, stream>>>(edge_idx, edge_feat,
                                                               cursor, sd2, ef2);
    node_proj_kernel<<<(N_NODES * H + 255) / 256, 256, 0, stream>>>(
        node_feat, W_np, b_np, h);

    // ---- 3 propagation steps (2 dispatches each) ----
    for (int step = 0; step < STEPS; ++step) {
        fused_msg_kernel<<<N_NODES / 16, 576, 0, stream>>>(
            W_e, b_e, h, rowptr, sd2, ef2, m);
        float* dst_h = (step == STEPS - 1) ? out : h;
        gru_kernel<<<N_NODES / 16, 256, 0, stream>>>(W_ih, W_hh, b_ih, b_hh,
                                                     m, h, dst_h);
    }
}

// Round 12
// 290.512 us; speedup vs baseline: 1.1492x; 1.0275x over previous
//
#include <hip/hip_runtime.h>
#include <math.h>

#define N_NODES 20000
#define N_EDGES 160000
#define NODE_DIM 64
#define EDGE_DIM 16
#define H 32
#define STEPS 3
#define NH (N_NODES * H)

// ---------------------------------------------------------------------------
// CSR-by-src build (R11 shape, proven 298us). fill copies the edge-feature
// row inline. 6 setup enqueues (single memset covers m replicas + cursor).
// ---------------------------------------------------------------------------
__global__ void hist_src_kernel(const int* __restrict__ ei, int* __restrict__ deg) {
    int e = blockIdx.x * 256 + threadIdx.x;
    if (e < N_EDGES) atomicAdd(&deg[ei[e]], 1);               // row 0 = src
}

__global__ void scan_a_kernel(const int* __restrict__ deg,
                              int* __restrict__ part, int* __restrict__ bsum) {
    __shared__ int s[256];
    int v = blockIdx.x * 256 + threadIdx.x;
    int x = (v < N_NODES) ? deg[v] : 0;
    s[threadIdx.x] = x;
    __syncthreads();
    for (int off = 1; off < 256; off <<= 1) {
        int t = (threadIdx.x >= off) ? s[threadIdx.x - off] : 0;
        __syncthreads();
        s[threadIdx.x] += t;
        __syncthreads();
    }
    if (v < N_NODES) part[v] = s[threadIdx.x] - x;
    if (threadIdx.x == 255) bsum[blockIdx.x] = s[255];
}

__global__ void scan_b_kernel(int* __restrict__ rowptr,
                              const int* __restrict__ bsum,
                              int* __restrict__ cursor) {
    __shared__ int boff[80];
    if (threadIdx.x == 0) {
        int run = 0;
        for (int b = 0; b < 79; ++b) { boff[b] = run; run += bsum[b]; }
    }
    __syncthreads();
    for (int v = threadIdx.x; v < N_NODES; v += 256) {
        int r = rowptr[v] + boff[v >> 8];
        rowptr[v] = r;
        cursor[v] = r;
    }
    if (threadIdx.x == 0) rowptr[N_NODES] = N_EDGES;
}

// fill + inline ef permute (scattered 64B row copies; saves a full pass)
__global__ void fill_src_kernel(const int* __restrict__ ei,
                                const float* __restrict__ ef,
                                int* __restrict__ cursor,
                                int2* __restrict__ sd2,
                                float* __restrict__ ef2) {
    int e = blockIdx.x * 256 + threadIdx.x;
    if (e < N_EDGES) {
        int s = ei[e];
        int slot = atomicAdd(&cursor[s], 1);
        sd2[slot] = make_int2(s, ei[N_EDGES + e]);
        const float4* __restrict__ srcp = (const float4*)(ef + (size_t)e * EDGE_DIM);
        float4* __restrict__ dstp       = (float4*)(ef2 + (size_t)slot * EDGE_DIM);
        float4 a = srcp[0], b = srcp[1], c = srcp[2], d = srcp[3];
        dstp[0] = a; dstp[1] = b; dstp[2] = c; dstp[3] = d;
    }
}

// ---------------------------------------------------------------------------
// node projection: h = node_feat @ W_np.T + b_np
// ---------------------------------------------------------------------------
__global__ void node_proj_kernel(const float* __restrict__ nf,
                                 const float* __restrict__ W,
                                 const float* __restrict__ b,
                                 float* __restrict__ h) {
    int tid = blockIdx.x * blockDim.x + threadIdx.x;
    if (tid >= N_NODES * H) return;
    int v = tid >> 5;
    int i = tid & 31;
    const float* __restrict__ row = nf + v * NODE_DIM;
    const float* __restrict__ w   = W + i * NODE_DIM;
    float acc = b[i];
#pragma unroll
    for (int d = 0; d < NODE_DIM; ++d) acc = fmaf(row[d], w[d], acc);
    h[tid] = acc;
}

// ---------------------------------------------------------------------------
// FUSED U-precompute + edge message (R7/R11 structure, proven best).
// NEW: atomic sink split across 2 m-replicas by edge parity (j&1) — tests
// whether the ~40us floor is per-line RMW serialization (deg~8 bursts of
// 32 f32 RMW per 128B line) vs global RMW rate. Replicas halve per-line
// bursts; gru sums both.
// ---------------------------------------------------------------------------
__global__ __launch_bounds__(576)
void fused_msg_kernel(const float* __restrict__ We,
                      const float* __restrict__ be,
                      const float* __restrict__ h,
                      const int* __restrict__ rowptr,
                      const int2* __restrict__ sd2,
                      const float* __restrict__ ef2,
                      float* __restrict__ m) {
    __shared__ float hs[16 * 32];     // 2 KB
    __shared__ float Ul[16 * 576];    // 36 KB (swizzled, 576-float row stride)

    int t = threadIdx.x;

    // ---- per-thread weight column (registers) ----
    float wreg[32];
    int p = -1;
    if (t < 512) {
        int L = t >> 4, q = (t >> 2) & 3, e = t & 3;
        int d = t & 15;
#pragma unroll
        for (int k = 0; k < H; ++k) wreg[k] = We[(L * H + k) * EDGE_DIM + d];
        p = q * 136 + L * 4 + e;
    } else if (t < 544) {
        int i = t - 512;
#pragma unroll
        for (int k = 0; k < H; ++k) wreg[k] = be[i * H + k];
        p = 544 + i;
    }

    int v0 = blockIdx.x * 16;

    // ---- stage h rows ----
    if (t < 512) hs[t] = h[(size_t)v0 * H + t];
    __syncthreads();

    // ---- phase 1: U into LDS (2 nodes per pass, broadcast f4 reads) ----
    if (p >= 0) {
        for (int n = 0; n < 16; n += 2) {
            const float4* __restrict__ hp0 = (const float4*)(hs + n * H);
            const float4* __restrict__ hp1 = (const float4*)(hs + (n + 1) * H);
            float a0 = 0.f, a1 = 0.f;
#pragma unroll
            for (int kk = 0; kk < 8; ++kk) {
                float4 q0 = hp0[kk];
                float4 q1 = hp1[kk];
                a0 = fmaf(wreg[4 * kk + 0], q0.x, a0);
                a1 = fmaf(wreg[4 * kk + 0], q1.x, a1);
                a0 = fmaf(wreg[4 * kk + 1], q0.y, a0);
                a1 = fmaf(wreg[4 * kk + 1], q1.y, a1);
                a0 = fmaf(wreg[4 * kk + 2], q0.z, a0);
                a1 = fmaf(wreg[4 * kk + 2], q1.z, a1);
                a0 = fmaf(wreg[4 * kk + 3], q0.w, a0);
                a1 = fmaf(wreg[4 * kk + 3], q1.w, a1);
            }
            Ul[n * 576 + p]       = a0;
            Ul[(n + 1) * 576 + p] = a1;
        }
    }
    __syncthreads();

    // ---- phase 2: contiguous chunks, reg-cached U, 1-deep prefetch ----
    int hw    = t >> 5;          // 0..17
    int lane  = t & 31;          // output component i
    int jbeg  = rowptr[v0];
    int jend  = rowptr[v0 + 16];
    int nE    = jend - jbeg;
    int chunk = (nE + 17) / 18;
    int ja    = jbeg + hw * chunk;
    int jz    = ja + chunk; if (jz > jend) jz = jend;

    if (ja < jz) {
        int s_prev = -1;
        float4 u0 = {0,0,0,0}, u1 = {0,0,0,0}, u2 = {0,0,0,0}, u3 = {0,0,0,0};
        float  bv = 0.f;

        int2 sd = sd2[ja];
        const float4* __restrict__ ep0 = (const float4*)(ef2 + (size_t)ja * EDGE_DIM);
        float4 e0 = ep0[0], e1 = ep0[1], e2 = ep0[2], e3 = ep0[3];

        for (int j = ja; j < jz; ++j) {
            // prefetch next edge (clamped -> no branch)
            int jn = (j + 1 < jz) ? (j + 1) : j;
            int2 sdn = sd2[jn];
            const float4* __restrict__ epn =
                (const float4*)(ef2 + (size_t)jn * EDGE_DIM);
            float4 f0 = epn[0], f1 = epn[1], f2 = epn[2], f3 = epn[3];

            // U regs reload only on src change
            if (sd.x != s_prev) {
                s_prev = sd.x;
                int ls = sd.x - v0;
                const float4* __restrict__ up = (const float4*)(Ul + ls * 576);
                u0 = up[0 * 34 + lane];
                u1 = up[1 * 34 + lane];
                u2 = up[2 * 34 + lane];
                u3 = up[3 * 34 + lane];
                bv = Ul[ls * 576 + 544 + lane];
            }

            float msg = bv;
            msg = fmaf(e0.x, u0.x, msg);
            msg = fmaf(e0.y, u0.y, msg);
            msg = fmaf(e0.z, u0.z, msg);
            msg = fmaf(e0.w, u0.w, msg);
            msg = fmaf(e1.x, u1.x, msg);
            msg = fmaf(e1.y, u1.y, msg);
            msg = fmaf(e1.z, u1.z, msg);
            msg = fmaf(e1.w, u1.w, msg);
            msg = fmaf(e2.x, u2.x, msg);
            msg = fmaf(e2.y, u2.y, msg);
            msg = fmaf(e2.z, u2.z, msg);
            msg = fmaf(e2.w, u2.w, msg);
            msg = fmaf(e3.x, u3.x, msg);
            msg = fmaf(e3.y, u3.y, msg);
            msg = fmaf(e3.z, u3.z, msg);
            msg = fmaf(e3.w, u3.w, msg);

            // replica-split atomic: halves per-line RMW bursts
            atomicAdd(&m[(size_t)(j & 1) * NH + (size_t)sd.y * H + lane], msg);

            sd = sdn;
            e0 = f0; e1 = f1; e2 = f2; e3 = f3;
        }
    }
}

// ---------------------------------------------------------------------------
// GRU (R7 core): register-weight column-GEMM. NEW: grid 625 x 2 tiles
// (removes scheduling tail at 1250>1024 capacity; weight load amortized 2x);
// phase A sums + zeroes BOTH m replicas.
// ---------------------------------------------------------------------------
__global__ __launch_bounds__(256, 4)
void gru_kernel(const float* __restrict__ Wih,
                const float* __restrict__ Whh,
                const float* __restrict__ bih,
                const float* __restrict__ bhh,
                float* __restrict__ m,
                const float* __restrict__ h,
                float* __restrict__ hout) {
    __shared__ float xs[16 * 64];        // [node][ m(32) | h(32) ]   4 KB
    __shared__ float gs[16 * 32 * 5];    // [node][i][gate + pad]    10 KB

    int c = threadIdx.x & 127;
    float4 wc[16];
    if (c < 96) {
        const float4* p = (const float4*)(Wih + c * H);
#pragma unroll
        for (int q = 0; q < 8; ++q) wc[q] = p[q];
    } else {
#pragma unroll
        for (int q = 0; q < 8; ++q) wc[q] = make_float4(0.f, 0.f, 0.f, 0.f);
    }
    int hrow = (c < 64) ? c : ((c >= 96) ? (c - 32) : -1);
    if (hrow >= 0) {
        const float4* p = (const float4*)(Whh + hrow * H);
#pragma unroll
        for (int q = 0; q < 8; ++q) wc[8 + q] = p[q];
    } else {
#pragma unroll
        for (int q = 0; q < 8; ++q) wc[8 + q] = make_float4(0.f, 0.f, 0.f, 0.f);
    }
    float bias;
    if (c < 64)      bias = bih[c] + bhh[c];      // r_sum / z_sum
    else if (c < 96) bias = bih[c];               // in
    else             bias = bhh[c - 32];          // hn

    int g    = threadIdx.x >> 5;    // node group 0..7
    int lane = threadIdx.x & 31;
    int half = threadIdx.x >> 7;    // 0: nodes 0..7, 1: nodes 8..15
    int ci   = c & 31;
    int gt   = c >> 5;

    for (int tile = 0; tile < 2; ++tile) {
        int v0 = (blockIdx.x * 2 + tile) * 16;

        // ---- phase A: read both m replicas (and zero them), stage h ----
#pragma unroll
        for (int nn = 0; nn < 2; ++nn) {
            int n = g + nn * 8;
            int v = v0 + n;
            size_t idx = (size_t)v * H + lane;
            float mv = m[idx] + m[NH + idx];
            m[idx]      = 0.f;               // pre-zero for next step
            m[NH + idx] = 0.f;
            xs[n * 64 + lane]      = mv;
            xs[n * 64 + 32 + lane] = h[idx];
        }
        __syncthreads();

        // ---- phase B: column-GEMM, 2 nodes per pass for ILP ----
#pragma unroll
        for (int n = 0; n < 8; n += 2) {
            const float4* x0 = (const float4*)(xs + (half * 8 + n) * 64);
            const float4* x1 = (const float4*)(xs + (half * 8 + n + 1) * 64);
            float acc0 = bias, acc1 = bias;
#pragma unroll
            for (int q = 0; q < 16; ++q) {
                float4 w = wc[q];
                float4 a = x0[q];
                float4 b = x1[q];
                acc0 = fmaf(w.x, a.x, acc0); acc1 = fmaf(w.x, b.x, acc1);
                acc0 = fmaf(w.y, a.y, acc0); acc1 = fmaf(w.y, b.y, acc1);
                acc0 = fmaf(w.z, a.z, acc0); acc1 = fmaf(w.z, b.z, acc1);
                acc0 = fmaf(w.w, a.w, acc0); acc1 = fmaf(w.w, b.w, acc1);
            }
            gs[((half * 8 + n)     * 32 + ci) * 5 + gt] = acc0;
            gs[((half * 8 + n + 1) * 32 + ci) * 5 + gt] = acc1;
        }
        __syncthreads();

        // ---- phase C: gates + output ----
        for (int t = threadIdx.x; t < 16 * 32; t += 256) {
            int nl = t >> 5, ii = t & 31;
            const float* gp = gs + (size_t)t * 5;
            float rs = gp[0], zs = gp[1], in_ = gp[2], hn = gp[3];
            float hv = xs[nl * 64 + 32 + ii];
            float r   = 1.f / (1.f + __expf(-rs));
            float z   = 1.f / (1.f + __expf(-zs));
            float nn2 = tanhf(in_ + r * hn);
            hout[(size_t)(v0 + nl) * H + ii] = (1.f - z) * nn2 + z * hv;
        }
        __syncthreads();   // xs/gs reused by next tile
    }
}

// ---------------------------------------------------------------------------
extern "C" void kernel_launch(void* const* d_in, const int* in_sizes, int n_in,
                              void* d_out, int out_size, void* d_ws, size_t ws_size,
                              hipStream_t stream) {
    const float* node_feat = (const float*)d_in[0];
    const int*   edge_idx  = (const int*)  d_in[1];
    const float* edge_feat = (const float*)d_in[2];
    const float* W_np      = (const float*)d_in[3];
    const float* b_np      = (const float*)d_in[4];
    const float* W_e       = (const float*)d_in[5];
    const float* b_e       = (const float*)d_in[6];
    const float* W_ih      = (const float*)d_in[7];
    const float* W_hh      = (const float*)d_in[8];
    const float* b_ih      = (const float*)d_in[9];
    const float* b_hh      = (const float*)d_in[10];

    float* h      = (float*)d_ws;                             // N*H
    float* m      = h + (size_t)NH;                           // 2 * N*H (replicas)
    int* cursor   = (int*)(m + 2 * (size_t)NH);               // N   (contig w/ m!)
    int* rowptr   = cursor + N_NODES;                         // N+2 (pad, even)
    int* bsum     = rowptr + (N_NODES + 2);                   // 82  (pad, even)
    int2* sd2     = (int2*)(bsum + 82);                       // E int2 (8B aligned)
    float* ef2    = (float*)(sd2 + N_EDGES);                  // E*EDGE_DIM
    float* out    = (float*)d_out;

    // ---- setup: 6 enqueues (single memset zeroes m replicas + cursor) ----
    hipMemsetAsync(m, 0, (2 * (size_t)NH + N_NODES) * sizeof(float), stream);
    hist_src_kernel<<<(N_EDGES + 255) / 256, 256, 0, stream>>>(edge_idx, cursor);
    scan_a_kernel<<<(N_NODES + 255) / 256, 256, 0, stream>>>(cursor, rowptr, bsum);
    scan_b_kernel<<<1, 256, 0, stream>>>(rowptr, bsum, cursor);
    fill_src_kernel<<<(N_EDGES + 255) / 256, 256, 0, stream>>>(edge_idx, edge_feat,
                                                               cursor, sd2, ef2);
    node_proj_kernel<<<(N_NODES * H + 255) / 256, 256, 0, stream>>>(
        node_feat, W_np, b_np, h);

    // ---- 3 propagation steps (2 dispatches each) ----
    for (int step = 0; step < STEPS; ++step) {
        fused_msg_kernel<<<N_NODES / 16, 576, 0, stream>>>(
            W_e, b_e, h, rowptr, sd2, ef2, m);
        float* dst_h = (step == STEPS - 1) ? out : h;
        gru_kernel<<<625, 256, 0, stream>>>(W_ih, W_hh, b_ih, b_hh,
                                            m, h, dst_h);
    }
}